// Round 2
// baseline (14087.465 us; speedup 1.0000x reference)
//
#include <hip/hip_runtime.h>
#include <cstdint>
#include <cstddef>

// ---------------------------------------------------------------------------
// RLSTM: B=32, T=1024, F=256, H=256.
// Identities: a_rec = a_cur[idx]; gate chunk 4 unused (o_t = i_t); x@W is
// recurrence-free (phase A). Phase B: 64 persistent WGs, each owns 4 h-cols
// (12 gate cols). Cross-WG traffic is ONLY hbank + flags, handled with
// per-access agent-scope atomics (sc0 sc1 -> coherent at L3) -- NO cache-wide
// fences (R1's agent fences invalidated L2 every step: 788 MB HBM refetch,
// 9.8 us/step). AX reads/writes are same-WG-only -> own L2, normal accesses.
// ---------------------------------------------------------------------------

#define T_STEPS 1024
#define BSZ 32
#define FDIM 256
#define HDIM 256
#define G3 768           // used gate cols (i,f,g chunks)
#define KWG 64           // phase-B workgroups (<=256 CUs -> co-resident)
#define HS 4             // h-cols per WG
#define JC 12            // gate cols per WG (3 chunks x HS)
#define HPAD 260         // LDS row pad (stride 260 floats: 16B aligned rows)
#define FLAG_STRIDE 32   // uints -> 128B per flag line
#define OMEGA 32

static const size_t AX_BYTES = (size_t)T_STEPS * BSZ * G3 * sizeof(float);         // 96 MiB
static const size_t HB_BYTES = (size_t)(T_STEPS + 1) * BSZ * HDIM * sizeof(float); // 32 MiB
static const size_t GX_BYTES = (size_t)T_STEPS * sizeof(double);

// ------------------------------ Phase A ------------------------------------
__global__ __launch_bounds__(256) void phaseA(const float* __restrict__ x,
                                              const float* __restrict__ W,
                                              const float* __restrict__ W_r,
                                              const float* __restrict__ P_r,
                                              float* __restrict__ AX,
                                              double* __restrict__ gx) {
  const int t = blockIdx.x;
  const int tid = threadIdx.x;
  __shared__ __align__(16) float xs[BSZ][HPAD];
  __shared__ double sred[BSZ];

  for (int i = tid; i < BSZ * FDIM / 4; i += 256) {
    const int b = (i * 4) >> 8;
    const int k = (i * 4) & 255;
    *(float4*)&xs[b][k] = *(const float4*)&x[((size_t)b * T_STEPS + t) * FDIM + k];
  }
  __syncthreads();

  for (int pass = 0; pass < 3; ++pass) {
    const int j = pass * 256 + tid;
    float acc[BSZ];
#pragma unroll
    for (int b = 0; b < BSZ; ++b) acc[b] = 0.f;
    for (int k0 = 0; k0 < FDIM; k0 += 4) {
      const float w0 = W[(size_t)(k0 + 0) * 1024 + j];
      const float w1 = W[(size_t)(k0 + 1) * 1024 + j];
      const float w2 = W[(size_t)(k0 + 2) * 1024 + j];
      const float w3 = W[(size_t)(k0 + 3) * 1024 + j];
#pragma unroll
      for (int b = 0; b < BSZ; ++b) {
        const float4 xv = *(const float4*)&xs[b][k0];  // LDS broadcast
        acc[b] = fmaf(xv.x, w0, acc[b]);
        acc[b] = fmaf(xv.y, w1, acc[b]);
        acc[b] = fmaf(xv.z, w2, acc[b]);
        acc[b] = fmaf(xv.w, w3, acc[b]);
      }
    }
    for (int b = 0; b < BSZ; ++b) AX[((size_t)t * BSZ + b) * G3 + j] = acc[b];
  }

  if (tid < BSZ) {
    double s = 0.0;
    for (int k = 0; k < FDIM; k += 4) {
      const float4 xv = *(const float4*)&xs[tid][k];
      const float4 wv = *(const float4*)&W_r[k];
      s = fma((double)xv.x, (double)wv.x, s);
      s = fma((double)xv.y, (double)wv.y, s);
      s = fma((double)xv.z, (double)wv.z, s);
      s = fma((double)xv.w, (double)wv.w, s);
    }
    sred[tid] = s;
  }
  __syncthreads();
  if (tid == 0) {
    double g = 0.0;
    for (int b = 0; b < BSZ; ++b) g = fma((double)P_r[b], sred[b], g);
    gx[t] = g;
  }
}

// ------------------------------ Phase B ------------------------------------
__global__ __launch_bounds__(256) void phaseB(const float* __restrict__ U,
                                              const float* __restrict__ P,
                                              const float* __restrict__ B_bias,
                                              const float* __restrict__ P_r,
                                              const float* __restrict__ U_r,
                                              float* __restrict__ AX,
                                              float* __restrict__ hbank,
                                              const double* __restrict__ gx,
                                              unsigned int* __restrict__ flags) {
  const int wg = blockIdx.x;
  const int tid = threadIdx.x;

  __shared__ __align__(16) float ULt[JC][HPAD];   // U cols for this WG, k-major
  __shared__ __align__(16) float hL[BSZ][HPAD];   // h_{t-1}
  __shared__ __align__(16) float PL[BSZ][64];
  __shared__ __align__(16) float acs[JC][36];     // a_cur slice [jc][b]
  __shared__ __align__(16) float ars[JC][36];     // a_rec slice
  __shared__ __align__(16) float ggs[JC][36];     // gate pre-activations
  __shared__ __align__(16) float UrL[FDIM];
  __shared__ float PrL[BSZ];
  __shared__ float biasL[JC];

  for (int i = tid; i < JC * HDIM; i += 256) {
    const int jc = i >> 8, k = i & 255;
    const int col = (jc >> 2) * HDIM + wg * HS + (jc & 3);
    ULt[jc][k] = U[(size_t)k * 1024 + col];
  }
  for (int i = tid; i < BSZ * 64; i += 256) PL[i >> 6][i & 63] = P[i];
  if (tid < FDIM) UrL[tid] = U_r[tid];
  if (tid < BSZ) PrL[tid] = P_r[tid];
  if (tid < JC) biasL[tid] = B_bias[(tid >> 2) * HDIM + wg * HS + (tid & 3)];

  // h@U mapping (waves 1..3): u in [0,192); items i=u and i=u+192 share jc,
  // batches bA and bA+16 -> one ULt column read serves both.
  const int u = (tid >= 64) ? (tid - 64) : 0;
  const int bA = u / JC, jcA = u % JC;
  const int colA = (jcA >> 2) * HDIM + wg * HS + (jcA & 3);
  const int bB = bA + 16;

  // P-mix mapping: items tid and tid+256 over i = b*JC + jc
  const int pb0 = tid / JC, pj0 = tid % JC;
  const int i1 = tid + 256;
  const int pb1 = i1 / JC, pj1 = i1 % JC;
  const bool act1 = (i1 < BSZ * JC);

  float creg = 0.f;  // c state: threads tid<128 own (b=tid>>2, hc=tid&3)
  __syncthreads();

  for (int t = 0; t < T_STEPS; ++t) {
    // ---- prefetch XW row t (own cols; own-L2/L3, no coherence needed) ----
    float xw0 = 0.f, xw1 = 0.f;
    size_t a0 = 0, a1 = 0;
    if (tid >= 64) {
      a0 = ((size_t)t * BSZ + bA) * G3 + colA;
      a1 = ((size_t)t * BSZ + bB) * G3 + colA;
      xw0 = AX[a0];
      xw1 = AX[a1];
    }
    double gxt = 0.0;
    if (tid == 0) gxt = gx[t];

    // ---- wait for all WGs to have published h_{t-1} ----------------------
    if (t > 0 && tid < KWG) {
      int guard = 0;
      while (__hip_atomic_load(&flags[tid * FLAG_STRIDE], __ATOMIC_RELAXED,
                               __HIP_MEMORY_SCOPE_AGENT) < (unsigned)t) {
        if (++guard > (1 << 22)) break;  // hang guard (never trips normally)
      }
    }
    __syncthreads();  // A

    // ---- load h_{t-1}: per-access coherent loads (bypass stale L1/L2) ----
    {
      const float* hsrc = hbank + (size_t)t * (BSZ * HDIM);
#pragma unroll
      for (int j = 0; j < 32; ++j) {
        const int i = tid + j * 256;
        const float v = __hip_atomic_load(&hsrc[i], __ATOMIC_RELAXED,
                                          __HIP_MEMORY_SCOPE_AGENT);
        hL[i >> 8][i & 255] = v;
      }
    }
    __syncthreads();  // B

    // ---- wave 0: recall gate (fp64, shuffle-reduced, deterministic) + ----
    // ---- a_rec prefetch into ars.  waves 1..3: h@U full-K + a_cur. -------
    if (tid < 64) {
      if (t >= OMEGA) {
        const int gb = tid & 31, kp = tid >> 5;
        double s = 0.0;
        const int k0 = kp * 128;
        for (int k = k0; k < k0 + 128; k += 4) {
          const float4 hv = *(const float4*)&hL[gb][k];
          const float4 uv = *(const float4*)&UrL[k];
          s = fma((double)hv.x, (double)uv.x, s);
          s = fma((double)hv.y, (double)uv.y, s);
          s = fma((double)hv.z, (double)uv.z, s);
          s = fma((double)hv.w, (double)uv.w, s);
        }
        s += __shfl_xor(s, 32, 64);           // lanes l and l^32 now equal
        double v = (double)PrL[gb] * s;
        v += __shfl_xor(v, 16, 64);
        v += __shfl_xor(v, 8, 64);
        v += __shfl_xor(v, 4, 64);
        v += __shfl_xor(v, 2, 64);
        v += __shfl_xor(v, 1, 64);
        int idx = 0;
        if (tid == 0) {
          const double g = gxt + v;
          const double gate = 1.0 / (1.0 + exp(-g));
          idx = (int)rint((double)t * gate);  // ties-to-even == jnp.round
          if (idx > t - 1) idx = t - 1;
          if (idx < 0) idx = 0;
        }
        idx = __shfl(idx, 0, 64);
        // a_rec = a_cur[idx] -- rows this WG itself wrote -> own L2 hit
        const size_t base = (size_t)idx * (BSZ * G3);
#pragma unroll
        for (int j = 0; j < 6; ++j) {
          const int i = tid + j * 64;
          const int b = i / JC, jc = i % JC;
          const int col = (jc >> 2) * HDIM + wg * HS + (jc & 3);
          ars[jc][b] = AX[base + (size_t)b * G3 + col];
        }
      }
    } else {
      float s0 = 0.f, s1 = 0.f;
      for (int k = 0; k < HDIM; k += 4) {
        const float4 uv = *(const float4*)&ULt[jcA][k];
        const float4 h0 = *(const float4*)&hL[bA][k];
        const float4 h1 = *(const float4*)&hL[bB][k];
        s0 = fmaf(h0.x, uv.x, s0); s0 = fmaf(h0.y, uv.y, s0);
        s0 = fmaf(h0.z, uv.z, s0); s0 = fmaf(h0.w, uv.w, s0);
        s1 = fmaf(h1.x, uv.x, s1); s1 = fmaf(h1.y, uv.y, s1);
        s1 = fmaf(h1.z, uv.z, s1); s1 = fmaf(h1.w, uv.w, s1);
      }
      const float v0 = s0 + xw0;
      const float v1 = s1 + xw1;
      AX[a0] = v0;              // a_cur into bank (read back later as a_rec)
      AX[a1] = v1;
      acs[jcA][bA] = v0;
      acs[jcA][bB] = v1;
      if (t < OMEGA) {          // use_self: a_rec == a_cur
        ars[jcA][bA] = v0;
        ars[jcA][bB] = v1;
      }
    }
    __syncthreads();  // C

    // ---- gates = P @ [a_cur; a_rec] + bias -------------------------------
    float g0;
    {
      float g = biasL[pj0];
#pragma unroll
      for (int b4 = 0; b4 < BSZ; b4 += 4) {
        const float4 pv = *(const float4*)&PL[pb0][b4];
        const float4 av = *(const float4*)&acs[pj0][b4];
        g = fmaf(pv.x, av.x, g); g = fmaf(pv.y, av.y, g);
        g = fmaf(pv.z, av.z, g); g = fmaf(pv.w, av.w, g);
      }
#pragma unroll
      for (int b4 = 0; b4 < BSZ; b4 += 4) {
        const float4 pv = *(const float4*)&PL[pb0][BSZ + b4];
        const float4 av = *(const float4*)&ars[pj0][b4];
        g = fmaf(pv.x, av.x, g); g = fmaf(pv.y, av.y, g);
        g = fmaf(pv.z, av.z, g); g = fmaf(pv.w, av.w, g);
      }
      g0 = g;
    }
    float g1 = 0.f;
    if (act1) {
      float g = biasL[pj1];
#pragma unroll
      for (int b4 = 0; b4 < BSZ; b4 += 4) {
        const float4 pv = *(const float4*)&PL[pb1][b4];
        const float4 av = *(const float4*)&acs[pj1][b4];
        g = fmaf(pv.x, av.x, g); g = fmaf(pv.y, av.y, g);
        g = fmaf(pv.z, av.z, g); g = fmaf(pv.w, av.w, g);
      }
#pragma unroll
      for (int b4 = 0; b4 < BSZ; b4 += 4) {
        const float4 pv = *(const float4*)&PL[pb1][BSZ + b4];
        const float4 av = *(const float4*)&ars[pj1][b4];
        g = fmaf(pv.x, av.x, g); g = fmaf(pv.y, av.y, g);
        g = fmaf(pv.z, av.z, g); g = fmaf(pv.w, av.w, g);
      }
      g1 = g;
    }
    ggs[pj0][pb0] = g0;
    if (act1) ggs[pj1][pb1] = g1;
    __syncthreads();  // E

    // ---- LSTM update + publish h_t (write-through coherent stores) -------
    if (tid < BSZ * HS) {
      const int b = tid >> 2, hc = tid & 3;
      const float gi = ggs[hc][b];
      const float gf = ggs[4 + hc][b];
      const float gg = ggs[8 + hc][b];
      const float iv = 1.f / (1.f + expf(-gi));
      const float fv = 1.f / (1.f + expf(-gf));
      const float gv = tanhf(gg);
      creg = fmaf(fv, creg, iv * gv);
      const float hv = iv * tanhf(creg);  // o_t = i_t (faithful to source)
      __hip_atomic_store(
          &hbank[(size_t)(t + 1) * (BSZ * HDIM) + (size_t)b * HDIM + wg * HS + hc],
          hv, __ATOMIC_RELAXED, __HIP_MEMORY_SCOPE_AGENT);
    }
    __builtin_amdgcn_s_waitcnt(0);  // drain publish stores to coherence point
    __syncthreads();                // F: all threads' stores drained
    if (tid == 0) {
      __hip_atomic_store(&flags[wg * FLAG_STRIDE], (unsigned)(t + 1),
                         __ATOMIC_RELAXED, __HIP_MEMORY_SCOPE_AGENT);
    }
  }
}

// ------------------------------ Output -------------------------------------
__global__ void outK(const float* __restrict__ hbank, const float* __restrict__ W_out,
                     const float* __restrict__ b_out, float* __restrict__ out) {
  const int b = threadIdx.x;
  if (b < BSZ) {
    const float* h = hbank + (size_t)T_STEPS * BSZ * HDIM + (size_t)b * HDIM;
    float s = 0.f;
    for (int k = 0; k < HDIM; k += 4) {
      const float4 hv = *(const float4*)&h[k];
      const float4 wv = *(const float4*)&W_out[k];
      s = fmaf(hv.x, wv.x, s); s = fmaf(hv.y, wv.y, s);
      s = fmaf(hv.z, wv.z, s); s = fmaf(hv.w, wv.w, s);
    }
    out[b] = s + b_out[0];
  }
}

// ------------------------------ Launch -------------------------------------
extern "C" void kernel_launch(void* const* d_in, const int* in_sizes, int n_in,
                              void* d_out, int out_size, void* d_ws, size_t ws_size,
                              hipStream_t stream) {
  const float* x      = (const float*)d_in[0];
  const float* W      = (const float*)d_in[1];
  const float* U      = (const float*)d_in[2];
  const float* P      = (const float*)d_in[3];
  const float* B_bias = (const float*)d_in[4];
  const float* W_r    = (const float*)d_in[5];
  const float* P_r    = (const float*)d_in[6];
  const float* U_r    = (const float*)d_in[7];
  const float* W_out  = (const float*)d_in[8];
  const float* b_out  = (const float*)d_in[9];

  char* ws = (char*)d_ws;
  float*    AX    = (float*)ws;
  float*    hbank = (float*)(ws + AX_BYTES);
  double*   gx    = (double*)(ws + AX_BYTES + HB_BYTES);
  unsigned* flags = (unsigned*)(ws + AX_BYTES + HB_BYTES + GX_BYTES);

  hipMemsetAsync(hbank, 0, (size_t)BSZ * HDIM * sizeof(float), stream);  // h0 = 0
  hipMemsetAsync(flags, 0, (size_t)KWG * FLAG_STRIDE * sizeof(unsigned), stream);

  phaseA<<<T_STEPS, 256, 0, stream>>>(x, W, W_r, P_r, AX, gx);
  phaseB<<<KWG, 256, 0, stream>>>(U, P, B_bias, P_r, U_r, AX, hbank, gx, flags);
  outK<<<1, 64, 0, stream>>>(hbank, W_out, b_out, (float*)d_out);
}

// Round 3
// 8277.445 us; speedup vs baseline: 1.7019x; 1.7019x over previous
//
#include <hip/hip_runtime.h>
#include <cstdint>
#include <cstddef>

// ---------------------------------------------------------------------------
// RLSTM: B=32, T=1024, F=256, H=256.
// Identities: a_rec = a_cur[idx]; gate chunk 4 unused (o_t = i_t); x@W is
// recurrence-free (phase A). Phase B: 64 persistent WGs, each owns 4 h-cols
// (12 gate cols). R3: minimize per-step sync critical path --
//   hbank [t][wg][b][c] contiguous -> b64 bypass loads (16/thread, batched),
//   wave-0-only publish (per-wave waitcnt, no barrier before flag),
//   packed flags (4 lines) polled by all waves w/ __all ballot (no barrier),
//   AXc [wg][t][384] contiguous (24 lines/step vs 96),
//   P-mix+LSTM folded into owner threads (3 barriers/step, was 5).
// ---------------------------------------------------------------------------

#define T_STEPS 1024
#define BSZ 32
#define FDIM 256
#define HDIM 256
#define G3W 384          // per-WG gate cols x batch (12*32) flat row
#define KWG 64           // phase-B workgroups (co-resident on 256 CUs)
#define HS 4             // h-cols per WG
#define JC 12            // gate cols per WG (3 chunks x HS)
#define HPAD 260         // LDS row pad
#define OMEGA 32
#define HSLICE 8192      // floats per hbank step slice (32*256)

static const size_t AXC_BYTES = (size_t)KWG * T_STEPS * G3W * sizeof(float);      // 96 MiB
static const size_t HB_BYTES  = (size_t)(T_STEPS + 1) * HSLICE * sizeof(float);   // 32 MiB
static const size_t GX_BYTES  = (size_t)T_STEPS * sizeof(double);

// ------------------------------ Phase A ------------------------------------
__global__ __launch_bounds__(256) void phaseA(const float* __restrict__ x,
                                              const float* __restrict__ W,
                                              const float* __restrict__ W_r,
                                              const float* __restrict__ P_r,
                                              float* __restrict__ AXc,
                                              double* __restrict__ gx) {
  const int t = blockIdx.x;
  const int tid = threadIdx.x;
  __shared__ __align__(16) float xs[BSZ][HPAD];
  __shared__ double sred[BSZ];

  for (int i = tid; i < BSZ * FDIM / 4; i += 256) {
    const int b = (i * 4) >> 8;
    const int k = (i * 4) & 255;
    *(float4*)&xs[b][k] = *(const float4*)&x[((size_t)b * T_STEPS + t) * FDIM + k];
  }
  __syncthreads();

  for (int pass = 0; pass < 3; ++pass) {
    const int j = pass * 256 + tid;           // gate col in [0,768)
    float acc[BSZ];
#pragma unroll
    for (int b = 0; b < BSZ; ++b) acc[b] = 0.f;
    for (int k0 = 0; k0 < FDIM; k0 += 4) {
      const float w0 = W[(size_t)(k0 + 0) * 1024 + j];
      const float w1 = W[(size_t)(k0 + 1) * 1024 + j];
      const float w2 = W[(size_t)(k0 + 2) * 1024 + j];
      const float w3 = W[(size_t)(k0 + 3) * 1024 + j];
#pragma unroll
      for (int b = 0; b < BSZ; ++b) {
        const float4 xv = *(const float4*)&xs[b][k0];  // LDS broadcast
        acc[b] = fmaf(xv.x, w0, acc[b]);
        acc[b] = fmaf(xv.y, w1, acc[b]);
        acc[b] = fmaf(xv.z, w2, acc[b]);
        acc[b] = fmaf(xv.w, w3, acc[b]);
      }
    }
    // AXc[wg][t][b*12 + slot], wg = (j%256)/4, slot = (j/256)*4 + j%4
    const int wgj = (j >> 2) & 63;
    const int slot = ((j >> 8) << 2) | (j & 3);
    float* dst = AXc + ((size_t)wgj * T_STEPS + t) * G3W + slot;
    for (int b = 0; b < BSZ; ++b) dst[b * 12] = acc[b];
  }

  if (tid < BSZ) {
    double s = 0.0;
    for (int k = 0; k < FDIM; k += 4) {
      const float4 xv = *(const float4*)&xs[tid][k];
      const float4 wv = *(const float4*)&W_r[k];
      s = fma((double)xv.x, (double)wv.x, s);
      s = fma((double)xv.y, (double)wv.y, s);
      s = fma((double)xv.z, (double)wv.z, s);
      s = fma((double)xv.w, (double)wv.w, s);
    }
    sred[tid] = s;
  }
  __syncthreads();
  if (tid == 0) {
    double g = 0.0;
    for (int b = 0; b < BSZ; ++b) g = fma((double)P_r[b], sred[b], g);
    gx[t] = g;
  }
}

// ------------------------------ Phase B ------------------------------------
__global__ __launch_bounds__(256) void phaseB(const float* __restrict__ U,
                                              const float* __restrict__ P,
                                              const float* __restrict__ B_bias,
                                              const float* __restrict__ P_r,
                                              const float* __restrict__ U_r,
                                              float* __restrict__ AXc,
                                              float* __restrict__ hbank,
                                              const double* __restrict__ gx,
                                              unsigned int* __restrict__ flags) {
  const int wg = blockIdx.x;
  const int tid = threadIdx.x;

  __shared__ __align__(16) float ULt[JC][HPAD];   // U cols for this WG, k-major
  __shared__ __align__(16) float hL[BSZ][HPAD];   // h_{t-1}, full
  __shared__ __align__(16) float PL[BSZ][64];
  __shared__ __align__(16) float acs[JC][36];     // a_cur slice [jc][b]
  __shared__ __align__(16) float ars[JC][36];     // a_rec slice
  __shared__ __align__(16) float hpub[BSZ * HS];  // our h slice [b*4+c]
  __shared__ __align__(16) float UrL[FDIM];
  __shared__ float PrL[BSZ];
  __shared__ float biasL[JC];

  for (int i = tid; i < JC * HDIM; i += 256) {
    const int jc = i >> 8, k = i & 255;
    const int col = (jc >> 2) * HDIM + wg * HS + (jc & 3);
    ULt[jc][k] = U[(size_t)k * 1024 + col];
  }
  for (int i = tid; i < BSZ * 64; i += 256) PL[i >> 6][i & 63] = P[i];
  if (tid < FDIM) UrL[tid] = U_r[tid];
  if (tid < BSZ) PrL[tid] = P_r[tid];
  if (tid < JC) biasL[tid] = B_bias[(tid >> 2) * HDIM + wg * HS + (tid & 3)];

  // h@U mapping (waves 1..3): u in [0,192): bA = u/12 in [0,16), jcA = u%12.
  // AXc flat index for (b,jc) is b*12+jc -> f0 = u, f1 = u + 192.
  const int u = (tid >= 64) ? (tid - 64) : 0;
  const int bA = u / JC, jcA = u % JC;
  const int bB = bA + 16;
  const int lane = tid & 63;

  float* __restrict__ AXwg = AXc + (size_t)wg * T_STEPS * G3W;

  float creg = 0.f;  // c state: threads tid<128 own (b=tid>>2, hc=tid&3)
  const int ob = tid >> 2, ohc = tid & 3;  // owner mapping for P-mix/LSTM
  __syncthreads();

  for (int t = 0; t < T_STEPS; ++t) {
    // ---- prefetch XW row t (own contiguous 1.5KB block) ------------------
    float xw0 = 0.f, xw1 = 0.f;
    size_t a0 = 0, a1 = 0;
    if (tid >= 64) {
      a0 = (size_t)t * G3W + u;
      a1 = a0 + 192;
      xw0 = AXwg[a0];
      xw1 = AXwg[a1];
    }
    double gxt = 0.0;
    if (tid == 0) gxt = gx[t];

    // ---- poll: all waves wait until all 64 flags reached t ---------------
    if (t > 0) {
      int guard = 0;
      for (;;) {
        const unsigned v = __hip_atomic_load(&flags[lane], __ATOMIC_RELAXED,
                                             __HIP_MEMORY_SCOPE_AGENT);
        if (__all((int)(v >= (unsigned)t))) break;
        if (++guard > (1 << 20)) break;  // hang guard (never trips normally)
      }
      asm volatile("" ::: "memory");  // pin: no hoisting loads above poll
    }

    // ---- gather h_{t-1}: 16 b64 bypass loads/thread, batched -------------
    {
      const unsigned long long* hsrc =
          (const unsigned long long*)(hbank + (size_t)t * HSLICE);
      unsigned long long u8[16];
#pragma unroll
      for (int j = 0; j < 16; ++j) {
        u8[j] = __hip_atomic_load(&hsrc[tid + j * 256], __ATOMIC_RELAXED,
                                  __HIP_MEMORY_SCOPE_AGENT);
      }
#pragma unroll
      for (int j = 0; j < 16; ++j) {
        const int i = tid + j * 256;      // ull index
        const int d = i * 2;              // dword index: [wg2][b][c]
        const int wg2 = d >> 7, r = d & 127, b = r >> 2, c = r & 3;  // c in {0,2}
        *(float2*)&hL[b][wg2 * HS + c] = __builtin_bit_cast(float2, u8[j]);
      }
    }
    __syncthreads();  // B: hL complete

    // ---- wave 0: recall gate (fp64) + a_rec prefetch ----------------------
    // ---- waves 1..3: h@U full-K, a_cur = XW + hU -------------------------
    if (tid < 64) {
      if (t >= OMEGA) {
        const int gb = tid & 31, kp = tid >> 5;
        double s = 0.0;
        const int k0 = kp * 128;
        for (int k = k0; k < k0 + 128; k += 4) {
          const float4 hv = *(const float4*)&hL[gb][k];
          const float4 uv = *(const float4*)&UrL[k];
          s = fma((double)hv.x, (double)uv.x, s);
          s = fma((double)hv.y, (double)uv.y, s);
          s = fma((double)hv.z, (double)uv.z, s);
          s = fma((double)hv.w, (double)uv.w, s);
        }
        s += __shfl_xor(s, 32, 64);
        double v = (double)PrL[gb] * s;
        v += __shfl_xor(v, 16, 64);
        v += __shfl_xor(v, 8, 64);
        v += __shfl_xor(v, 4, 64);
        v += __shfl_xor(v, 2, 64);
        v += __shfl_xor(v, 1, 64);
        int idx = 0;
        if (tid == 0) {
          const double g = gxt + v;
          const double gate = 1.0 / (1.0 + exp(-g));
          idx = (int)rint((double)t * gate);  // ties-to-even == jnp.round
          if (idx > t - 1) idx = t - 1;
          if (idx < 0) idx = 0;
        }
        idx = __shfl(idx, 0, 64);
        // a_rec = a_cur[idx]: contiguous 1.5KB block in our own AXc region
        const float* __restrict__ src = AXwg + (size_t)idx * G3W;
        float av[6];
#pragma unroll
        for (int j = 0; j < 6; ++j) av[j] = src[tid + j * 64];
#pragma unroll
        for (int j = 0; j < 6; ++j) {
          const int f = tid + j * 64;
          ars[f % JC][f / JC] = av[j];
        }
      }
    } else {
      float s0 = 0.f, s1 = 0.f;
      for (int k = 0; k < HDIM; k += 4) {
        const float4 uv = *(const float4*)&ULt[jcA][k];
        const float4 h0 = *(const float4*)&hL[bA][k];
        const float4 h1 = *(const float4*)&hL[bB][k];
        s0 = fmaf(h0.x, uv.x, s0); s0 = fmaf(h0.y, uv.y, s0);
        s0 = fmaf(h0.z, uv.z, s0); s0 = fmaf(h0.w, uv.w, s0);
        s1 = fmaf(h1.x, uv.x, s1); s1 = fmaf(h1.y, uv.y, s1);
        s1 = fmaf(h1.z, uv.z, s1); s1 = fmaf(h1.w, uv.w, s1);
      }
      const float v0 = s0 + xw0;
      const float v1 = s1 + xw1;
      AXwg[a0] = v0;            // a_cur into bank (read back later as a_rec)
      AXwg[a1] = v1;
      acs[jcA][bA] = v0;
      acs[jcA][bB] = v1;
      if (t < OMEGA) {          // use_self: a_rec == a_cur
        ars[jcA][bA] = v0;
        ars[jcA][bB] = v1;
      }
    }
    __syncthreads();  // C: acs/ars complete

    // ---- owner threads: gates = P @ [a_cur; a_rec] + bias, LSTM, publish --
    if (tid < BSZ * HS) {
      float gi = biasL[ohc];
      float gf = biasL[4 + ohc];
      float gg = biasL[8 + ohc];
#pragma unroll
      for (int b4 = 0; b4 < BSZ; b4 += 4) {
        const float4 pv = *(const float4*)&PL[ob][b4];
        const float4 ai = *(const float4*)&acs[ohc][b4];
        const float4 af = *(const float4*)&acs[4 + ohc][b4];
        const float4 ag = *(const float4*)&acs[8 + ohc][b4];
        gi = fmaf(pv.x, ai.x, gi); gi = fmaf(pv.y, ai.y, gi);
        gi = fmaf(pv.z, ai.z, gi); gi = fmaf(pv.w, ai.w, gi);
        gf = fmaf(pv.x, af.x, gf); gf = fmaf(pv.y, af.y, gf);
        gf = fmaf(pv.z, af.z, gf); gf = fmaf(pv.w, af.w, gf);
        gg = fmaf(pv.x, ag.x, gg); gg = fmaf(pv.y, ag.y, gg);
        gg = fmaf(pv.z, ag.z, gg); gg = fmaf(pv.w, ag.w, gg);
      }
#pragma unroll
      for (int b4 = 0; b4 < BSZ; b4 += 4) {
        const float4 pv = *(const float4*)&PL[ob][BSZ + b4];
        const float4 ai = *(const float4*)&ars[ohc][b4];
        const float4 af = *(const float4*)&ars[4 + ohc][b4];
        const float4 ag = *(const float4*)&ars[8 + ohc][b4];
        gi = fmaf(pv.x, ai.x, gi); gi = fmaf(pv.y, ai.y, gi);
        gi = fmaf(pv.z, ai.z, gi); gi = fmaf(pv.w, ai.w, gi);
        gf = fmaf(pv.x, af.x, gf); gf = fmaf(pv.y, af.y, gf);
        gf = fmaf(pv.z, af.z, gf); gf = fmaf(pv.w, af.w, gf);
        gg = fmaf(pv.x, ag.x, gg); gg = fmaf(pv.y, ag.y, gg);
        gg = fmaf(pv.z, ag.z, gg); gg = fmaf(pv.w, ag.w, gg);
      }
      const float iv = 1.f / (1.f + expf(-gi));
      const float fv = 1.f / (1.f + expf(-gf));
      const float gv = tanhf(gg);
      creg = fmaf(fv, creg, iv * gv);
      hpub[tid] = iv * tanhf(creg);  // o_t = i_t (faithful to source)
    }
    __syncthreads();  // F: hpub complete

    // ---- wave 0 publishes slice + flag (per-wave waitcnt only) -----------
    if (tid < 64) {
      const unsigned long long u8 = *(const unsigned long long*)&hpub[tid * 2];
      unsigned long long* hdst = (unsigned long long*)(hbank +
          (size_t)(t + 1) * HSLICE + (size_t)wg * (BSZ * HS));
      __hip_atomic_store(&hdst[tid], u8, __ATOMIC_RELAXED,
                         __HIP_MEMORY_SCOPE_AGENT);
      __builtin_amdgcn_s_waitcnt(0);  // drain this wave's 64 stores
      if (tid == 0) {
        __hip_atomic_store(&flags[wg], (unsigned)(t + 1), __ATOMIC_RELAXED,
                           __HIP_MEMORY_SCOPE_AGENT);
      }
    }
  }
}

// ------------------------------ Output -------------------------------------
__global__ void outK(const float* __restrict__ hbank, const float* __restrict__ W_out,
                     const float* __restrict__ b_out, float* __restrict__ out) {
  const int b = threadIdx.x;
  if (b < BSZ) {
    const float* h = hbank + (size_t)T_STEPS * HSLICE;  // [wg][b][c]
    float s = 0.f;
    for (int wg = 0; wg < KWG; ++wg) {
      const float4 hv = *(const float4*)&h[wg * (BSZ * HS) + b * HS];
      const float4 wv = *(const float4*)&W_out[wg * HS];
      s = fmaf(hv.x, wv.x, s); s = fmaf(hv.y, wv.y, s);
      s = fmaf(hv.z, wv.z, s); s = fmaf(hv.w, wv.w, s);
    }
    out[b] = s + b_out[0];
  }
}

// ------------------------------ Launch -------------------------------------
extern "C" void kernel_launch(void* const* d_in, const int* in_sizes, int n_in,
                              void* d_out, int out_size, void* d_ws, size_t ws_size,
                              hipStream_t stream) {
  const float* x      = (const float*)d_in[0];
  const float* W      = (const float*)d_in[1];
  const float* U      = (const float*)d_in[2];
  const float* P      = (const float*)d_in[3];
  const float* B_bias = (const float*)d_in[4];
  const float* W_r    = (const float*)d_in[5];
  const float* P_r    = (const float*)d_in[6];
  const float* U_r    = (const float*)d_in[7];
  const float* W_out  = (const float*)d_in[8];
  const float* b_out  = (const float*)d_in[9];

  char* ws = (char*)d_ws;
  float*    AXc   = (float*)ws;
  float*    hbank = (float*)(ws + AXC_BYTES);
  double*   gx    = (double*)(ws + AXC_BYTES + HB_BYTES);
  unsigned* flags = (unsigned*)(ws + AXC_BYTES + HB_BYTES + GX_BYTES);

  hipMemsetAsync(hbank, 0, (size_t)HSLICE * sizeof(float), stream);  // h0 = 0
  hipMemsetAsync(flags, 0, (size_t)KWG * sizeof(unsigned), stream);

  phaseA<<<T_STEPS, 256, 0, stream>>>(x, W, W_r, P_r, AXc, gx);
  phaseB<<<KWG, 256, 0, stream>>>(U, P, B_bias, P_r, U_r, AXc, hbank, gx, flags);
  outK<<<1, 64, 0, stream>>>(hbank, W_out, b_out, (float*)d_out);
}